// Round 21
// baseline (107.151 us; speedup 1.0000x reference)
//
#include <hip/hip_runtime.h>
#include <stdint.h>

// DILATE loss, B=32, L=512, DIM=16, gamma=1e-3, alpha=0.5.
//
// Round-21 = R19 VERBATIM (105.8us, absmax 0.0) with ONE change: kA runs
// 8 blocks/batch (was 32) -> 4x less inp/tgt re-read, same inner code.
// R20's three fused trims (dpp-old-operand fusion, capture peel, atomic
// out-fusion) are reverted: R20 failed with absmax consistent with the
// dpp fusion zeroing the up-handoff; re-bank the proven baseline.
//
//   kA : Dsk2[b][q][i*2+(j&1)], q=j/2+i/2; transposed-x LDS (conflict-free
//        ds_read_b64), fully-coalesced f32x2 stores.
//   kP : 32 blocks x 256 thr (4 waves), skew-2 wavefront, doubly-skewed
//        coalesced loads (one dwordx4/lane/step), 8 asm slots w/ counted
//        vmcnt(7), DPP in-wave handoff, 64-slot LDS ring + barrier per
//        8 steps. T[i,j] = T[argmin parent] + (i-j)^2.
//   kC : combine -> scalar loss.
// Junk cells: clamped loads/poison -> fmax(D,0)=0 -> R_junk=1e10 exactly;
// inert. Tie priority: diag > up > left.

#define N 512
#define NB 32
#define BIGF 1e10f
#define QN 512
#define STRF2 ((size_t)QN * 1024)      // floats per batch (2 MiB)
#define VOMAX2 ((int)(STRF2 * 4 - 16))

typedef unsigned int u32;
typedef float f32x4 __attribute__((ext_vector_type(4)));
typedef float f32x2 __attribute__((ext_vector_type(2)));

__device__ __forceinline__ float dppshr(float x, float oldv) {
    // lane l gets lane l-1's x; lane 0 keeps oldv (bound_ctrl=false)
    return __int_as_float(__builtin_amdgcn_update_dpp(
        __float_as_int(oldv), __float_as_int(x), 0x138, 0xF, 0xF, false));
}

// ---------------- kA: transposed-x LDS, coalesced stores, 8 blocks/batch ---
__global__ __launch_bounds__(512) void kA(const float* __restrict__ inp,
                                          const float* __restrict__ tgt,
                                          float* __restrict__ Dg) {
    const int b = blockIdx.y;
    const int qbase = blockIdx.x * 64;  // q-group
    const int tid = (int)threadIdx.x;   // row index i in [0,512)
    __shared__ float xt[16 * 512];      // x transposed: xt[d*512 + j]

    {   // stage x[j] = inp[b,j] - inp[b,0], transposed
        const float4* ip = (const float4*)(inp + (((size_t)b * N + tid) << 4));
        const float4* op = (const float4*)(inp + (((size_t)b * N) << 4));
        float4 v0 = ip[0], v1 = ip[1], v2 = ip[2], v3 = ip[3];
        float4 o0 = op[0], o1 = op[1], o2 = op[2], o3 = op[3];
        xt[0 * 512 + tid] = v0.x - o0.x;   xt[1 * 512 + tid] = v0.y - o0.y;
        xt[2 * 512 + tid] = v0.z - o0.z;   xt[3 * 512 + tid] = v0.w - o0.w;
        xt[4 * 512 + tid] = v1.x - o1.x;   xt[5 * 512 + tid] = v1.y - o1.y;
        xt[6 * 512 + tid] = v1.z - o1.z;   xt[7 * 512 + tid] = v1.w - o1.w;
        xt[8 * 512 + tid] = v2.x - o2.x;   xt[9 * 512 + tid] = v2.y - o2.y;
        xt[10 * 512 + tid] = v2.z - o2.z;  xt[11 * 512 + tid] = v2.w - o2.w;
        xt[12 * 512 + tid] = v3.x - o3.x;  xt[13 * 512 + tid] = v3.y - o3.y;
        xt[14 * 512 + tid] = v3.z - o3.z;  xt[15 * 512 + tid] = v3.w - o3.w;
    }
    __syncthreads();

    const float4* t4 = (const float4*)(tgt + (((size_t)b * N + tid) << 4));
    float4 ta = t4[0], tb = t4[1], tc = t4[2], td = t4[3];
    const float tr[16] = {ta.x, ta.y, ta.z, ta.w, tb.x, tb.y, tb.z, tb.w,
                          tc.x, tc.y, tc.z, tc.w, td.x, td.y, td.z, td.w};
    float* outB = Dg + (size_t)b * STRF2;

#pragma unroll 4
    for (int qi = 0; qi < 64; ++qi) {
        const int q = qbase + qi;
        const int g = q - (tid >> 1);
        if ((unsigned)g > 255u) continue;
        const int j0 = 2 * g;
        float sA = 0.f, sB = 0.f;
#pragma unroll
        for (int d = 0; d < 16; ++d) {
            f32x2 xv = *(const f32x2*)(xt + d * 512 + j0);
            float e0 = tr[d] - xv.x; sA = fmaf(e0, e0, sA);
            float e1 = tr[d] - xv.y; sB = fmaf(e1, e1, sB);
        }
        f32x2 wv; wv.x = sA; wv.y = sB;
        *(f32x2*)(outB + (size_t)q * 1024 + tid * 2) = wv;
    }
}

// ---------------- kP: 4-wave skew-2 pipelined wavefront DP (R15 verbatim) --
__global__ __launch_bounds__(256) void kP(const float* __restrict__ Dg,
                                          float* __restrict__ acc) {
    const int b = blockIdx.x;
    const int tid = (int)threadIdx.x;
    const int w = tid >> 6, lam = tid & 63;
    const float* __restrict__ Db = Dg + (size_t)b * STRF2;

    __shared__ __align__(16) f32x2 ring[3][64];
    __shared__ __align__(16) f32x2 dump2[72];

    for (int i = tid; i < 3 * 64 + 72; i += 256) {
        f32x2 z; z.x = BIGF; z.y = 0.f;
        ((f32x2*)ring)[i] = z;
    }
    __syncthreads();

    // 8 load slots; slot k covers steps s == k (mod 8).
    // voffset = (s - 16w)*4096 + tid*16, clamped at issue.
    int vo0, vo1, vo2, vo3, vo4, vo5, vo6, vo7;
    f32x4 d0, d1, d2, d3, d4, d5, d6, d7;
    {
        const int vb = tid * 16 - 16 * w * 4096;
        vo0 = vb;            vo1 = vb + 4096;     vo2 = vb + 2 * 4096;
        vo3 = vb + 3 * 4096; vo4 = vb + 4 * 4096; vo5 = vb + 5 * 4096;
        vo6 = vb + 6 * 4096; vo7 = vb + 7 * 4096;
    }

#define LOAD(k)                                                               \
    do {                                                                      \
        int va_ = min(max(vo##k, 0), VOMAX2);                                 \
        asm volatile("global_load_dwordx4 %0, %1, %2"                         \
                     : "=v"(d##k) : "v"(va_), "s"(Db));                       \
    } while (0)

    LOAD(0); LOAD(1); LOAD(2); LOAD(3); LOAD(4); LOAD(5); LOAD(6); LOAD(7);

    // DP state
    float L0R = BIGF, L1R = BIGF, L0T = 0.f, L1T = 0.f;  // own cols at c1
    float hA = BIGF, hB = BIGF, hAT = 0.f, hBT = 0.f;    // dpp handoffs
    float sBold = (tid == 0) ? 0.f : BIGF, sBoldT = 0.f; // diag for (r0,c0)
    float dr = (float)(4 * tid + 32 * w);                // (i-j) at (r0,c0)
    int pp = -(tid + 16 * w);                            // pair index
    float Rfin = 0.f, Tfin = 0.f;

    const bool is_cons = (lam == 0) && (w > 0);
    f32x2* base2 = ((lam == 63) && (w < 3)) ? &ring[w][0] : &dump2[0];
    const f32x2* ringR = (w > 0) ? &ring[w - 1][0] : &ring[0][0];
    int rb = (-160 * w) & 63;

    f32x4 bkA[4], bkB[4];

#define READBANK(X)                                                           \
    do {                                                                      \
        if (is_cons) {                                                        \
            X[0] = *(const f32x4*)(ringR + (rb & 63));                        \
            X[1] = *(const f32x4*)(ringR + ((rb + 2) & 63));                  \
            X[2] = *(const f32x4*)(ringR + ((rb + 4) & 63));                  \
            X[3] = *(const f32x4*)(ringR + ((rb + 6) & 63));                  \
        }                                                                     \
        rb = (rb + 8) & 63;                                                   \
    } while (0)

    READBANK(bkA);  // prime: handoff data for steps 0..3

    // d layout: d.x=D(r0,c0) d.y=D(r0,c1) d.z=D(r1,c0) d.w=D(r1,c1)
#define STEP(k, BX, j)                                                        \
    do {                                                                      \
        asm volatile("s_waitcnt vmcnt(7)" : "+v"(d##k));                      \
        float D00 = fmaxf(d##k.x, 0.f), D01 = fmaxf(d##k.y, 0.f);             \
        float D10 = fmaxf(d##k.z, 0.f), D11 = fmaxf(d##k.w, 0.f);             \
        float upA = is_cons ? BX[j].x : hA;                                   \
        float utA = is_cons ? BX[j].y : hAT;                                  \
        float upB = is_cons ? BX[j].z : hB;                                   \
        float utB = is_cons ? BX[j].w : hBT;                                  \
        /* (r0,c0): up=upA dg=sBold lf=L0 */                                  \
        float mn0 = fminf(upA, fminf(sBold, L0R));                            \
        float Ts0 = (mn0 == sBold) ? sBoldT : ((mn0 == upA) ? utA : L0T);     \
        float R00 = D00 + mn0;                                                \
        float T00 = fmaf(dr, dr, Ts0);                                        \
        /* (r1,c0): up=R00 dg=L0 lf=L1 */                                     \
        float mn1 = fminf(R00, fminf(L0R, L1R));                              \
        float Ts1 = (mn1 == L0R) ? L0T : ((mn1 == R00) ? T00 : L1T);          \
        float drp = dr + 1.f;                                                 \
        float R10 = D10 + mn1;                                                \
        float T10 = fmaf(drp, drp, Ts1);                                      \
        /* (r0,c1): up=upB dg=upA lf=R00 */                                   \
        float mn2 = fminf(upB, fminf(upA, R00));                              \
        float Ts2 = (mn2 == upA) ? utA : ((mn2 == upB) ? utB : T00);          \
        float drm = dr - 1.f;                                                 \
        float R01 = D01 + mn2;                                                \
        float T01 = fmaf(drm, drm, Ts2);                                      \
        /* (r1,c1): up=R01 dg=R00 lf=R10 */                                   \
        float mn3 = fminf(R01, fminf(R00, R10));                              \
        float Ts3 = (mn3 == R00) ? T00 : ((mn3 == R01) ? T01 : T10);          \
        float R11v = D11 + mn3;                                               \
        float T11v = fmaf(dr, dr, Ts3);                                       \
        bool hit = (pp == 255);                                               \
        Rfin = hit ? R11v : Rfin;                                             \
        Tfin = hit ? T11v : Tfin;                                             \
        {                                                                     \
            int c0_ = 2 * pp;                                                 \
            f32x4 wv; wv.x = R10; wv.y = T10; wv.z = R11v; wv.w = T11v;       \
            *(f32x4*)(base2 + (c0_ & 63)) = wv;                               \
        }                                                                     \
        L0R = R01; L0T = T01; L1R = R11v; L1T = T11v;                         \
        sBold = upB; sBoldT = utB;                                            \
        hA = dppshr(R10, BIGF); hAT = dppshr(T10, 0.f);                       \
        hB = dppshr(R11v, BIGF); hBT = dppshr(T11v, 0.f);                     \
        dr -= 2.f; pp += 1;                                                   \
        vo##k += 32768; /* +8 q-blocks for this slot's next use */            \
        LOAD(k);                                                              \
    } while (0)

    for (int n = 0; n < 70; ++n) {  // 560 steps; lane 255 capture at s=558
        asm volatile("s_waitcnt lgkmcnt(0)" ::: "memory");
        __builtin_amdgcn_s_barrier();
        READBANK(bkB);  // handoff data for steps 8n+4..8n+7
        STEP(0, bkA, 0); STEP(1, bkA, 1); STEP(2, bkA, 2); STEP(3, bkA, 3);
        READBANK(bkA);  // handoff data for steps 8(n+1)..8(n+1)+3
        STEP(4, bkB, 0); STEP(5, bkB, 1); STEP(6, bkB, 2); STEP(7, bkB, 3);
    }
#undef STEP
#undef READBANK
#undef LOAD

    asm volatile("s_waitcnt vmcnt(0)" ::: "memory");  // drain before exit
    if (tid == 255) {
        acc[b] = Rfin;       // hard-DTW value Rp[N,N]
        acc[NB + b] = Tfin;  // sum (i-j)^2 along argmin path
    }
}

// ---------------- kC: combine over batches ---------------------------------
__global__ void kC(const float* __restrict__ acc, float* __restrict__ out) {
    const int l = (int)threadIdx.x;
    float vs = (l < NB) ? acc[l] : 0.f;
    float vt = (l < NB) ? acc[NB + l] : 0.f;
#pragma unroll
    for (int o = 32; o >= 1; o >>= 1) {
        vs += __shfl_down(vs, o);
        vt += __shfl_down(vt, o);
    }
    if (l == 0)
        out[0] = 0.5f * (vs / (float)NB) +
                 0.5f * (vt / ((float)NB * (float)(N * N)));
}

__global__ void kSentinel(float* out) { out[0] = -12345.0f; }

extern "C" void kernel_launch(void* const* d_in, const int* in_sizes, int n_in,
                              void* d_out, int out_size, void* d_ws, size_t ws_size,
                              hipStream_t stream) {
    const float* inp = (const float*)d_in[0];
    const float* tgt = (const float*)d_in[1];
    float* out = (float*)d_out;

    const size_t DSZ = (size_t)NB * STRF2 * sizeof(float);  // 64 MiB
    const size_t NEEDED = 256 + DSZ;
    if (ws_size < NEEDED) {
        kSentinel<<<1, 1, 0, stream>>>(out);
        return;
    }
    char* ws = (char*)d_ws;
    float* acc = (float*)ws;  // [0..31] shape, [32..63] temporal
    float* Dg = (float*)(ws + 256);

    kA<<<dim3(8, NB), 512, 0, stream>>>(inp, tgt, Dg);
    kP<<<NB, 256, 0, stream>>>(Dg, acc);
    kC<<<1, 64, 0, stream>>>(acc, out);
}